// Round 3
// baseline (82.483 us; speedup 1.0000x reference)
//
#include <hip/hip_runtime.h>

#define BB 4096
#define TT 80
#define VV 10000
#define EE 100
#define HH 64
#define RR 8     // real batch rows per block (MFMA rows 8..15 are ghost copies)
#define STR 72   // u16 row stride in LDS state arrays

typedef __attribute__((ext_vector_type(8))) short s8v;   // 8 bf16
typedef __attribute__((ext_vector_type(4))) float f4v;   // 4 fp32

#define MFMA(a, b, c) __builtin_amdgcn_mfma_f32_16x16x32_bf16((a), (b), (c), 0, 0, 0)

// Raw barrier: drains LDS writes (lgkm) but lets global gather loads stay in
// flight across the barrier (no vmcnt(0) drain like __syncthreads emits).
#define BAR() do { asm volatile("s_waitcnt lgkmcnt(0)" ::: "memory"); \
                   __builtin_amdgcn_s_barrier();                      \
                   asm volatile("" ::: "memory"); } while (0)

__device__ __forceinline__ unsigned f2u(float f) { return __float_as_uint(f); }
__device__ __forceinline__ float u2f(unsigned u) { return __uint_as_float(u); }

// tanh(x) = 1 - 2/(exp(2x)+1). No clamp needed: x=+big -> e=inf -> 1;
// x=-big -> e=0 -> -1. Inputs are always finite.
__device__ __forceinline__ float fast_tanh(float x) {
    float e = __builtin_amdgcn_exp2f(x * 2.8853900817779268f); // exp(2x)
    return 1.0f - 2.0f * __builtin_amdgcn_rcpf(e + 1.0f);
}

__device__ __forceinline__ s8v mk8(unsigned a, unsigned b, unsigned c, unsigned d) {
    union { unsigned u[4]; s8v s; } t;
    t.u[0] = a; t.u[1] = b; t.u[2] = c; t.u[3] = d;
    return t.s;
}

// Split hi/lo u16 state store: h = hi(bf16) + resid(bf16)
__device__ __forceinline__ void put_state(unsigned short* Hh, unsigned short* Hl,
                                          float h) {
    unsigned bits = f2u(h);
    float resid = h - u2f(bits & 0xffff0000u);
    *Hh = (unsigned short)(bits >> 16);
    *Hl = (unsigned short)(f2u(resid) >> 16);
}

// B-fragment (hi/lo) for W[k][c]: frag elem i <- W[32*kf + 8*g + i][c]
__device__ __forceinline__ void load_wfrag(const float* __restrict__ W, int kf, int g,
                                           int c, s8v& hi, s8v& lo) {
    unsigned wb[8], rb[8];
#pragma unroll
    for (int i = 0; i < 8; ++i) {
        float wv = W[(32 * kf + 8 * g + i) * HH + c];
        unsigned bits = f2u(wv);
        float hif = u2f(bits & 0xffff0000u);
        float resid = wv - hif;
        wb[i] = bits;
        rb[i] = f2u(resid);
    }
    hi = mk8((wb[0] >> 16) | (wb[1] & 0xffff0000u),
             (wb[2] >> 16) | (wb[3] & 0xffff0000u),
             (wb[4] >> 16) | (wb[5] & 0xffff0000u),
             (wb[6] >> 16) | (wb[7] & 0xffff0000u));
    lo = mk8((rb[0] >> 16) | (rb[1] & 0xffff0000u),
             (rb[2] >> 16) | (rb[3] & 0xffff0000u),
             (rb[4] >> 16) | (rb[5] & 0xffff0000u),
             (rb[6] >> 16) | (rb[7] & 0xffff0000u));
}

// emb2[v][j] = sum_e emb[v][e] * Wx0[e][j] + b0[j]
__global__ __launch_bounds__(256) void emb2_kernel(const float* __restrict__ emb,
                                                   const float* __restrict__ Wx0,
                                                   const float* __restrict__ b0,
                                                   float* __restrict__ emb2) {
    __shared__ float embL[16 * EE];
    const int v0 = blockIdx.x * 16;
    for (int i = threadIdx.x; i < 16 * EE; i += 256)
        embL[i] = emb[(size_t)v0 * EE + i];
    __syncthreads();
    const int wid = threadIdx.x >> 6;
    const int lane = threadIdx.x & 63;
    const float bb = b0[lane];
    float a0 = bb, a1 = bb, a2 = bb, a3 = bb;
    const float* e0 = &embL[(4 * wid) * EE];
#pragma unroll 4
    for (int e = 0; e < EE; ++e) {
        float w = Wx0[e * HH + lane];
        a0 = fmaf(e0[e], w, a0);
        a1 = fmaf(e0[e + EE], w, a1);
        a2 = fmaf(e0[e + 2 * EE], w, a2);
        a3 = fmaf(e0[e + 3 * EE], w, a3);
    }
    const int r = v0 + 4 * wid;
    emb2[(size_t)(r + 0) * HH + lane] = a0;
    emb2[(size_t)(r + 1) * HH + lane] = a1;
    emb2[(size_t)(r + 2) * HH + lane] = a2;
    emb2[(size_t)(r + 3) * HH + lane] = a3;
}

// Merged-role pipeline with ghost rows: 512 blocks (2 independent blocks/CU),
// 4 waves/block, 8 real batch rows + 8 ghost rows (exact copies of rows 0-7,
// via row&7 token duplication). Each wave owns one 16-col tile of BOTH layers.
// Raw s_barrier (lgkm drain only) lets x-gathers span barriers.
__global__ __launch_bounds__(256, 2) void rnn_pipe(
    const int* __restrict__ tokens, const float* __restrict__ emb2,
    const float* __restrict__ Wh0, const float* __restrict__ Wx1,
    const float* __restrict__ Wh1, const float* __restrict__ b1,
    const float* __restrict__ Wout, const float* __restrict__ bout,
    float* __restrict__ out) {
    __shared__ __align__(16) unsigned short H0H[2][16][STR];
    __shared__ __align__(16) unsigned short H0L[2][16][STR];
    __shared__ __align__(16) unsigned short H1H[2][16][STR];
    __shared__ __align__(16) unsigned short H1L[2][16][STR];
    __shared__ int tokB[RR * TT];   // byte-scaled (<<8)

    const int tid = threadIdx.x;
    const int wid = tid >> 6;        // 0..3 : column tile
    const int l = tid & 63;
    const int g = l >> 4;
    const int r16 = l & 15;
    const int c = 16 * wid + r16;    // my output column
    const int R = blockIdx.x * RR;   // base batch row

    for (int i = tid; i < RR * TT; i += 256) tokB[i] = tokens[R * TT + i] << 8;

    s8v wh0h[2], wh0l[2], wx1h[2], wx1l[2], wh1h[2], wh1l[2];
    load_wfrag(Wh0, 0, g, c, wh0h[0], wh0l[0]);
    load_wfrag(Wh0, 1, g, c, wh0h[1], wh0l[1]);
    load_wfrag(Wx1, 0, g, c, wx1h[0], wx1l[0]);
    load_wfrag(Wx1, 1, g, c, wx1h[1], wx1l[1]);
    load_wfrag(Wh1, 0, g, c, wh1h[0], wh1l[0]);
    load_wfrag(Wh1, 1, g, c, wh1h[1], wh1l[1]);
    const float b1j = b1[c];
    const float woj = Wout[l];
    const s8v z8 = mk8(0u, 0u, 0u, 0u);
    const f4v z4 = {0.f, 0.f, 0.f, 0.f};

    // token-row offsets (ghost groups g>=2 mirror rows 0-7)
    int trowTT[4];
#pragma unroll
    for (int q = 0; q < 4; ++q) trowTT[q] = ((4 * g + q) & 7) * TT;
    const char* ebase = (const char*)emb2 + 4 * c;

    BAR();   // tokens staged

    s8v a0h[2] = {z8, z8}, a0l[2] = {z8, z8};   // h0(p-1) fragments
    s8v a1h[2] = {z8, z8}, a1l[2] = {z8, z8};   // h1(p-2) fragments

    f4v xc, xn;
#pragma unroll
    for (int q = 0; q < 4; ++q)
        xc[q] = *(const float*)(ebase + tokB[trowTT[q]]);
#pragma unroll
    for (int q = 0; q < 4; ++q)
        xn[q] = *(const float*)(ebase + tokB[trowTT[q] + 1]);

    // ---- phase 0: h0(0) = tanh(x0) ----
#pragma unroll
    for (int q = 0; q < 4; ++q)
        put_state(&H0H[0][4 * g + q][c], &H0L[0][4 * g + q][c], fast_tanh(xc[q]));
    xc = xn;
    BAR();
    a0h[0] = *(const s8v*)&H0H[0][r16][8 * g];
    a0h[1] = *(const s8v*)&H0H[0][r16][32 + 8 * g];
    a0l[0] = *(const s8v*)&H0L[0][r16][8 * g];
    a0l[1] = *(const s8v*)&H0L[0][r16][32 + 8 * g];
    // a1 stays zero (h1(-1) = 0)

    // ---- main loop p = 1..TT-2 ----
#pragma unroll 2
    for (int p = 1; p <= TT - 2; ++p) {
        const int par = p & 1;
        // prefetch x(p+1); loads stay in flight across the barrier below,
        // waited (compiler-counted) only at next phase's use.
#pragma unroll
        for (int q = 0; q < 4; ++q)
            xn[q] = *(const float*)(ebase + tokB[trowTT[q] + p + 1]);
        // L0: h0(p) — 2 chains of 3
        f4v A1 = {xc[0], xc[1], xc[2], xc[3]};
        A1 = MFMA(a0h[0], wh0h[0], A1);
        A1 = MFMA(a0h[1], wh0h[1], A1);
        A1 = MFMA(a0l[0], wh0h[0], A1);
        f4v A2 = z4;
        A2 = MFMA(a0l[1], wh0h[1], A2);
        A2 = MFMA(a0h[0], wh0l[0], A2);
        A2 = MFMA(a0h[1], wh0l[1], A2);
        // L1: h1(p-1) — 4 chains of 3 (reuses a0 fragments)
        f4v C1 = {b1j, b1j, b1j, b1j};
        C1 = MFMA(a0h[0], wx1h[0], C1);
        C1 = MFMA(a0h[1], wx1h[1], C1);
        C1 = MFMA(a0l[0], wx1h[0], C1);
        f4v C2 = z4;
        C2 = MFMA(a0l[1], wx1h[1], C2);
        C2 = MFMA(a0h[0], wx1l[0], C2);
        C2 = MFMA(a0h[1], wx1l[1], C2);
        f4v C3 = z4;
        C3 = MFMA(a1h[0], wh1h[0], C3);
        C3 = MFMA(a1h[1], wh1h[1], C3);
        C3 = MFMA(a1l[0], wh1h[0], C3);
        f4v C4 = z4;
        C4 = MFMA(a1l[1], wh1h[1], C4);
        C4 = MFMA(a1h[0], wh1l[0], C4);
        C4 = MFMA(a1h[1], wh1l[1], C4);
        f4v acc0 = A1 + A2;
        f4v acc1 = (C1 + C2) + (C3 + C4);
#pragma unroll
        for (int q = 0; q < 4; ++q) {
            put_state(&H0H[par][4 * g + q][c], &H0L[par][4 * g + q][c],
                      fast_tanh(acc0[q]));
            put_state(&H1H[par][4 * g + q][c], &H1L[par][4 * g + q][c],
                      fast_tanh(acc1[q]));
        }
        xc = xn;
        BAR();
        a0h[0] = *(const s8v*)&H0H[par][r16][8 * g];
        a0h[1] = *(const s8v*)&H0H[par][r16][32 + 8 * g];
        a0l[0] = *(const s8v*)&H0L[par][r16][8 * g];
        a0l[1] = *(const s8v*)&H0L[par][r16][32 + 8 * g];
        a1h[0] = *(const s8v*)&H1H[par][r16][8 * g];
        a1h[1] = *(const s8v*)&H1H[par][r16][32 + 8 * g];
        a1l[0] = *(const s8v*)&H1L[par][r16][8 * g];
        a1l[1] = *(const s8v*)&H1L[par][r16][32 + 8 * g];
    }

    // ---- p = TT-1 = 79 (par 1): both layers, no prefetch ----
    {
        f4v A1 = {xc[0], xc[1], xc[2], xc[3]};
        A1 = MFMA(a0h[0], wh0h[0], A1);
        A1 = MFMA(a0h[1], wh0h[1], A1);
        A1 = MFMA(a0l[0], wh0h[0], A1);
        f4v A2 = z4;
        A2 = MFMA(a0l[1], wh0h[1], A2);
        A2 = MFMA(a0h[0], wh0l[0], A2);
        A2 = MFMA(a0h[1], wh0l[1], A2);
        f4v C1 = {b1j, b1j, b1j, b1j};
        C1 = MFMA(a0h[0], wx1h[0], C1);
        C1 = MFMA(a0h[1], wx1h[1], C1);
        C1 = MFMA(a0l[0], wx1h[0], C1);
        f4v C2 = z4;
        C2 = MFMA(a0l[1], wx1h[1], C2);
        C2 = MFMA(a0h[0], wx1l[0], C2);
        C2 = MFMA(a0h[1], wx1l[1], C2);
        f4v C3 = z4;
        C3 = MFMA(a1h[0], wh1h[0], C3);
        C3 = MFMA(a1h[1], wh1h[1], C3);
        C3 = MFMA(a1l[0], wh1h[0], C3);
        f4v C4 = z4;
        C4 = MFMA(a1l[1], wh1h[1], C4);
        C4 = MFMA(a1h[0], wh1l[0], C4);
        C4 = MFMA(a1h[1], wh1l[1], C4);
        f4v acc0 = A1 + A2;
        f4v acc1 = (C1 + C2) + (C3 + C4);
#pragma unroll
        for (int q = 0; q < 4; ++q) {
            put_state(&H0H[1][4 * g + q][c], &H0L[1][4 * g + q][c],
                      fast_tanh(acc0[q]));
            put_state(&H1H[1][4 * g + q][c], &H1L[1][4 * g + q][c],
                      fast_tanh(acc1[q]));
        }
        BAR();
        a0h[0] = *(const s8v*)&H0H[1][r16][8 * g];
        a0h[1] = *(const s8v*)&H0H[1][r16][32 + 8 * g];
        a0l[0] = *(const s8v*)&H0L[1][r16][8 * g];
        a0l[1] = *(const s8v*)&H0L[1][r16][32 + 8 * g];
        a1h[0] = *(const s8v*)&H1H[1][r16][8 * g];
        a1h[1] = *(const s8v*)&H1H[1][r16][32 + 8 * g];
        a1l[0] = *(const s8v*)&H1L[1][r16][8 * g];
        a1l[1] = *(const s8v*)&H1L[1][r16][32 + 8 * g];
    }

    // ---- p = TT = 80: L1 only -> h1(79) into buffer 0 ----
    {
        f4v C1 = {b1j, b1j, b1j, b1j};
        C1 = MFMA(a0h[0], wx1h[0], C1);
        C1 = MFMA(a0h[1], wx1h[1], C1);
        C1 = MFMA(a0l[0], wx1h[0], C1);
        f4v C2 = z4;
        C2 = MFMA(a0l[1], wx1h[1], C2);
        C2 = MFMA(a0h[0], wx1l[0], C2);
        C2 = MFMA(a0h[1], wx1l[1], C2);
        f4v C3 = z4;
        C3 = MFMA(a1h[0], wh1h[0], C3);
        C3 = MFMA(a1h[1], wh1h[1], C3);
        C3 = MFMA(a1l[0], wh1h[0], C3);
        f4v C4 = z4;
        C4 = MFMA(a1l[1], wh1h[1], C4);
        C4 = MFMA(a1h[0], wh1l[0], C4);
        C4 = MFMA(a1h[1], wh1l[1], C4);
        f4v acc1 = (C1 + C2) + (C3 + C4);
#pragma unroll
        for (int q = 0; q < 4; ++q)
            put_state(&H1H[0][4 * g + q][c], &H1L[0][4 * g + q][c],
                      fast_tanh(acc1[q]));
        BAR();
    }

    // Epilogue: out = sigmoid(h1(79) @ Wout + bout). Wave wid -> rows 2wid..+1
    // (rows 0..7 are the real rows).
#pragma unroll
    for (int q = 0; q < 2; ++q) {
        int row = 2 * wid + q;
        float v = u2f(((unsigned)H1H[0][row][l]) << 16) +
                  u2f(((unsigned)H1L[0][row][l]) << 16);
        float pp = v * woj;
#pragma unroll
        for (int off = 32; off > 0; off >>= 1) pp += __shfl_xor(pp, off, 64);
        if (l == 0) {
            float logit = pp + bout[0];
            out[R + row] = __builtin_amdgcn_rcpf(
                1.0f + __builtin_amdgcn_exp2f(-1.4426950408889634f * logit));
        }
    }
}

extern "C" void kernel_launch(void* const* d_in, const int* in_sizes, int n_in,
                              void* d_out, int out_size, void* d_ws, size_t ws_size,
                              hipStream_t stream) {
    const int*   tokens = (const int*)  d_in[0];
    const float* emb    = (const float*)d_in[1];
    const float* Wx0    = (const float*)d_in[2];
    const float* Wh0    = (const float*)d_in[3];
    const float* b0     = (const float*)d_in[4];
    const float* Wx1    = (const float*)d_in[5];
    const float* Wh1    = (const float*)d_in[6];
    const float* b1     = (const float*)d_in[7];
    const float* Wout   = (const float*)d_in[8];
    const float* bout   = (const float*)d_in[9];
    float* out  = (float*)d_out;
    float* emb2 = (float*)d_ws;   // VV*HH floats = 2.56 MB

    emb2_kernel<<<VV / 16, 256, 0, stream>>>(emb, Wx0, b0, emb2);
    rnn_pipe<<<BB / RR, 256, 0, stream>>>(tokens, emb2, Wh0, Wx1, Wh1, b1,
                                          Wout, bout, out);
}

// Round 4
// 62.813 us; speedup vs baseline: 1.3132x; 1.3132x over previous
//
#include <hip/hip_runtime.h>

#define BB 4096
#define TT 80
#define VV 10000
#define EE 100
#define HH 64
#define STR 68   // u16 row stride: 4-row group stride = 136 u16 = 8 (mod 32) dwords
                 // -> the 4 lane-groups write disjoint bank octets (conflict-free)

typedef __attribute__((ext_vector_type(8))) short s8v;   // 8 bf16
typedef __attribute__((ext_vector_type(4))) float f4v;   // 4 fp32
typedef __attribute__((ext_vector_type(4))) int i4v;     // 4 i32

#define MFMA(a, b, c) __builtin_amdgcn_mfma_f32_16x16x32_bf16((a), (b), (c), 0, 0, 0)

// Raw barrier: drains LDS writes (lgkm) but lets global gather loads stay in
// flight across the barrier (no vmcnt(0) drain like __syncthreads emits).
#define BAR() do { asm volatile("s_waitcnt lgkmcnt(0)" ::: "memory"); \
                   __builtin_amdgcn_s_barrier();                      \
                   asm volatile("" ::: "memory"); } while (0)

__device__ __forceinline__ unsigned f2u(float f) { return __float_as_uint(f); }
__device__ __forceinline__ float u2f(unsigned u) { return __uint_as_float(u); }

// tanh(x) = 1 - 2/(exp(2x)+1). No clamp: +big -> e=inf -> 1; -big -> e=0 -> -1.
// (verified numerically in R3: absmax unchanged)
__device__ __forceinline__ float fast_tanh(float x) {
    float e = __builtin_amdgcn_exp2f(x * 2.8853900817779268f); // exp(2x)
    return 1.0f - 2.0f * __builtin_amdgcn_rcpf(e + 1.0f);
}

__device__ __forceinline__ s8v mk8(unsigned a, unsigned b, unsigned c, unsigned d) {
    union { unsigned u[4]; s8v s; } t;
    t.u[0] = a; t.u[1] = b; t.u[2] = c; t.u[3] = d;
    return t.s;
}

// Split hi/lo u16 state store: h = hi(bf16) + resid(bf16)
__device__ __forceinline__ void put_state(unsigned short* Hh, unsigned short* Hl,
                                          float h) {
    unsigned bits = f2u(h);
    float resid = h - u2f(bits & 0xffff0000u);
    *Hh = (unsigned short)(bits >> 16);          // ds_write_b16_d16_hi candidate
    *Hl = (unsigned short)(f2u(resid) >> 16);
}

// B-fragment (hi/lo) for W[k][c]: frag elem i <- W[32*kf + 8*g + i][c]
__device__ __forceinline__ void load_wfrag(const float* __restrict__ W, int kf, int g,
                                           int c, s8v& hi, s8v& lo) {
    unsigned wb[8], rb[8];
#pragma unroll
    for (int i = 0; i < 8; ++i) {
        float wv = W[(32 * kf + 8 * g + i) * HH + c];
        unsigned bits = f2u(wv);
        float hif = u2f(bits & 0xffff0000u);
        float resid = wv - hif;
        wb[i] = bits;
        rb[i] = f2u(resid);
    }
    hi = mk8((wb[0] >> 16) | (wb[1] & 0xffff0000u),
             (wb[2] >> 16) | (wb[3] & 0xffff0000u),
             (wb[4] >> 16) | (wb[5] & 0xffff0000u),
             (wb[6] >> 16) | (wb[7] & 0xffff0000u));
    lo = mk8((rb[0] >> 16) | (rb[1] & 0xffff0000u),
             (rb[2] >> 16) | (rb[3] & 0xffff0000u),
             (rb[4] >> 16) | (rb[5] & 0xffff0000u),
             (rb[6] >> 16) | (rb[7] & 0xffff0000u));
}

// emb2[v][j] = sum_e emb[v][e] * Wx0[e][j] + b0[j]
__global__ __launch_bounds__(256) void emb2_kernel(const float* __restrict__ emb,
                                                   const float* __restrict__ Wx0,
                                                   const float* __restrict__ b0,
                                                   float* __restrict__ emb2) {
    __shared__ float embL[16 * EE];
    const int v0 = blockIdx.x * 16;
    for (int i = threadIdx.x; i < 16 * EE; i += 256)
        embL[i] = emb[(size_t)v0 * EE + i];
    __syncthreads();
    const int wid = threadIdx.x >> 6;
    const int lane = threadIdx.x & 63;
    const float bb = b0[lane];
    float a0 = bb, a1 = bb, a2 = bb, a3 = bb;
    const float* e0 = &embL[(4 * wid) * EE];
#pragma unroll 4
    for (int e = 0; e < EE; ++e) {
        float w = Wx0[e * HH + lane];
        a0 = fmaf(e0[e], w, a0);
        a1 = fmaf(e0[e + EE], w, a1);
        a2 = fmaf(e0[e + 2 * EE], w, a2);
        a3 = fmaf(e0[e + 3 * EE], w, a3);
    }
    const int r = v0 + 4 * wid;
    emb2[(size_t)(r + 0) * HH + lane] = a0;
    emb2[(size_t)(r + 1) * HH + lane] = a1;
    emb2[(size_t)(r + 2) * HH + lane] = a2;
    emb2[(size_t)(r + 3) * HH + lane] = a3;
}

// R1 structure + isolated latency fixes: 256 blocks, 4 waves, 16 REAL rows.
// Each wave owns one 16-col tile of BOTH layers:
//   h0(p)   = tanh(x(p) + h0(p-1)@Wh0)
//   h1(p-1) = tanh(b1 + h0(p-1)@Wx1 + h1(p-2)@Wh1)
// One raw barrier per phase (lgkm drain only); split hi/lo u16 state arrays
// (no perms on the read->MFMA path); transposed token table (1 broadcast
// b128/phase); depth-3 MFMA chains.
__global__ __launch_bounds__(256, 1) void rnn_pipe(
    const int* __restrict__ tokens, const float* __restrict__ emb2,
    const float* __restrict__ Wh0, const float* __restrict__ Wx1,
    const float* __restrict__ Wh1, const float* __restrict__ b1,
    const float* __restrict__ Wout, const float* __restrict__ bout,
    float* __restrict__ out) {
    __shared__ __align__(16) unsigned short H0H[2][16][STR];
    __shared__ __align__(16) unsigned short H0L[2][16][STR];
    __shared__ __align__(16) unsigned short H1H[2][16][STR];
    __shared__ __align__(16) unsigned short H1L[2][16][STR];
    __shared__ __align__(16) int tokT[TT][16];   // [t][row], byte-scaled (<<8)

    const int tid = threadIdx.x;
    const int wid = tid >> 6;        // 0..3 : column tile
    const int l = tid & 63;
    const int g = l >> 4;
    const int r16 = l & 15;
    const int c = 16 * wid + r16;    // my output column
    const int R = blockIdx.x * 16;   // base batch row

    for (int i = tid; i < 16 * TT; i += 256) {
        int r = i / TT, t = i - r * TT;
        tokT[t][r] = tokens[R * TT + i] << 8;
    }

    s8v wh0h[2], wh0l[2], wx1h[2], wx1l[2], wh1h[2], wh1l[2];
    load_wfrag(Wh0, 0, g, c, wh0h[0], wh0l[0]);
    load_wfrag(Wh0, 1, g, c, wh0h[1], wh0l[1]);
    load_wfrag(Wx1, 0, g, c, wx1h[0], wx1l[0]);
    load_wfrag(Wx1, 1, g, c, wx1h[1], wx1l[1]);
    load_wfrag(Wh1, 0, g, c, wh1h[0], wh1l[0]);
    load_wfrag(Wh1, 1, g, c, wh1h[1], wh1l[1]);
    const float b1j = b1[c];
    const float woj = Wout[l];
    const s8v z8 = mk8(0u, 0u, 0u, 0u);
    const f4v z4 = {0.f, 0.f, 0.f, 0.f};
    const char* ebase = (const char*)emb2 + 4 * c;

    BAR();   // tokens staged (lgkm only; weight loads are lane-private)

    s8v a0h[2] = {z8, z8}, a0l[2] = {z8, z8};   // h0(p-1) fragments
    s8v a1h[2] = {z8, z8}, a1l[2] = {z8, z8};   // h1(p-2) fragments

    f4v xc, xn;
    {
        i4v tk0 = *(const i4v*)&tokT[0][4 * g];
        i4v tk1 = *(const i4v*)&tokT[1][4 * g];
#pragma unroll
        for (int q = 0; q < 4; ++q)
            xc[q] = *(const float*)(ebase + tk0[q]);
#pragma unroll
        for (int q = 0; q < 4; ++q)
            xn[q] = *(const float*)(ebase + tk1[q]);
    }

    // ---- phase 0: h0(0) = tanh(x0) ----
#pragma unroll
    for (int q = 0; q < 4; ++q)
        put_state(&H0H[0][4 * g + q][c], &H0L[0][4 * g + q][c], fast_tanh(xc[q]));
    xc = xn;
    BAR();
    a0h[0] = *(const s8v*)&H0H[0][r16][8 * g];
    a0h[1] = *(const s8v*)&H0H[0][r16][32 + 8 * g];
    a0l[0] = *(const s8v*)&H0L[0][r16][8 * g];
    a0l[1] = *(const s8v*)&H0L[0][r16][32 + 8 * g];
    // a1 stays zero (h1(-1) = 0)

    // ---- main loop p = 1..TT-2 ----
#pragma unroll 2
    for (int p = 1; p <= TT - 2; ++p) {
        const int par = p & 1;
        // prefetch x(p+1): 1 broadcast b128 token read + 4 gathers; the
        // gathers stay in flight across BAR, waited at next phase's use.
        i4v tk = *(const i4v*)&tokT[p + 1][4 * g];
#pragma unroll
        for (int q = 0; q < 4; ++q)
            xn[q] = *(const float*)(ebase + tk[q]);
        // L0: h0(p) — 2 chains of 3
        f4v A1 = {xc[0], xc[1], xc[2], xc[3]};
        A1 = MFMA(a0h[0], wh0h[0], A1);
        A1 = MFMA(a0h[1], wh0h[1], A1);
        A1 = MFMA(a0l[0], wh0h[0], A1);
        f4v A2 = z4;
        A2 = MFMA(a0l[1], wh0h[1], A2);
        A2 = MFMA(a0h[0], wh0l[0], A2);
        A2 = MFMA(a0h[1], wh0l[1], A2);
        // L1: h1(p-1) — 4 chains of 3 (reuses a0 fragments)
        f4v C1 = {b1j, b1j, b1j, b1j};
        C1 = MFMA(a0h[0], wx1h[0], C1);
        C1 = MFMA(a0h[1], wx1h[1], C1);
        C1 = MFMA(a0l[0], wx1h[0], C1);
        f4v C2 = z4;
        C2 = MFMA(a0l[1], wx1h[1], C2);
        C2 = MFMA(a0h[0], wx1l[0], C2);
        C2 = MFMA(a0h[1], wx1l[1], C2);
        f4v C3 = z4;
        C3 = MFMA(a1h[0], wh1h[0], C3);
        C3 = MFMA(a1h[1], wh1h[1], C3);
        C3 = MFMA(a1l[0], wh1h[0], C3);
        f4v C4 = z4;
        C4 = MFMA(a1l[1], wh1h[1], C4);
        C4 = MFMA(a1h[0], wh1l[0], C4);
        C4 = MFMA(a1h[1], wh1l[1], C4);
        f4v acc0 = A1 + A2;
        f4v acc1 = (C1 + C2) + (C3 + C4);
#pragma unroll
        for (int q = 0; q < 4; ++q) {
            put_state(&H0H[par][4 * g + q][c], &H0L[par][4 * g + q][c],
                      fast_tanh(acc0[q]));
            put_state(&H1H[par][4 * g + q][c], &H1L[par][4 * g + q][c],
                      fast_tanh(acc1[q]));
        }
        xc = xn;
        BAR();
        a0h[0] = *(const s8v*)&H0H[par][r16][8 * g];
        a0h[1] = *(const s8v*)&H0H[par][r16][32 + 8 * g];
        a0l[0] = *(const s8v*)&H0L[par][r16][8 * g];
        a0l[1] = *(const s8v*)&H0L[par][r16][32 + 8 * g];
        a1h[0] = *(const s8v*)&H1H[par][r16][8 * g];
        a1h[1] = *(const s8v*)&H1H[par][r16][32 + 8 * g];
        a1l[0] = *(const s8v*)&H1L[par][r16][8 * g];
        a1l[1] = *(const s8v*)&H1L[par][r16][32 + 8 * g];
    }

    // ---- p = TT-1 = 79 (par 1): both layers, no prefetch ----
    {
        f4v A1 = {xc[0], xc[1], xc[2], xc[3]};
        A1 = MFMA(a0h[0], wh0h[0], A1);
        A1 = MFMA(a0h[1], wh0h[1], A1);
        A1 = MFMA(a0l[0], wh0h[0], A1);
        f4v A2 = z4;
        A2 = MFMA(a0l[1], wh0h[1], A2);
        A2 = MFMA(a0h[0], wh0l[0], A2);
        A2 = MFMA(a0h[1], wh0l[1], A2);
        f4v C1 = {b1j, b1j, b1j, b1j};
        C1 = MFMA(a0h[0], wx1h[0], C1);
        C1 = MFMA(a0h[1], wx1h[1], C1);
        C1 = MFMA(a0l[0], wx1h[0], C1);
        f4v C2 = z4;
        C2 = MFMA(a0l[1], wx1h[1], C2);
        C2 = MFMA(a0h[0], wx1l[0], C2);
        C2 = MFMA(a0h[1], wx1l[1], C2);
        f4v C3 = z4;
        C3 = MFMA(a1h[0], wh1h[0], C3);
        C3 = MFMA(a1h[1], wh1h[1], C3);
        C3 = MFMA(a1l[0], wh1h[0], C3);
        f4v C4 = z4;
        C4 = MFMA(a1l[1], wh1h[1], C4);
        C4 = MFMA(a1h[0], wh1l[0], C4);
        C4 = MFMA(a1h[1], wh1l[1], C4);
        f4v acc0 = A1 + A2;
        f4v acc1 = (C1 + C2) + (C3 + C4);
#pragma unroll
        for (int q = 0; q < 4; ++q) {
            put_state(&H0H[1][4 * g + q][c], &H0L[1][4 * g + q][c],
                      fast_tanh(acc0[q]));
            put_state(&H1H[1][4 * g + q][c], &H1L[1][4 * g + q][c],
                      fast_tanh(acc1[q]));
        }
        BAR();
        a0h[0] = *(const s8v*)&H0H[1][r16][8 * g];
        a0h[1] = *(const s8v*)&H0H[1][r16][32 + 8 * g];
        a0l[0] = *(const s8v*)&H0L[1][r16][8 * g];
        a0l[1] = *(const s8v*)&H0L[1][r16][32 + 8 * g];
        a1h[0] = *(const s8v*)&H1H[1][r16][8 * g];
        a1h[1] = *(const s8v*)&H1H[1][r16][32 + 8 * g];
        a1l[0] = *(const s8v*)&H1L[1][r16][8 * g];
        a1l[1] = *(const s8v*)&H1L[1][r16][32 + 8 * g];
    }

    // ---- p = TT = 80: L1 only -> h1(79) into buffer 0 ----
    {
        f4v C1 = {b1j, b1j, b1j, b1j};
        C1 = MFMA(a0h[0], wx1h[0], C1);
        C1 = MFMA(a0h[1], wx1h[1], C1);
        C1 = MFMA(a0l[0], wx1h[0], C1);
        f4v C2 = z4;
        C2 = MFMA(a0l[1], wx1h[1], C2);
        C2 = MFMA(a0h[0], wx1l[0], C2);
        C2 = MFMA(a0h[1], wx1l[1], C2);
        f4v C3 = z4;
        C3 = MFMA(a1h[0], wh1h[0], C3);
        C3 = MFMA(a1h[1], wh1h[1], C3);
        C3 = MFMA(a1l[0], wh1h[0], C3);
        f4v C4 = z4;
        C4 = MFMA(a1l[1], wh1h[1], C4);
        C4 = MFMA(a1h[0], wh1l[0], C4);
        C4 = MFMA(a1h[1], wh1l[1], C4);
        f4v acc1 = (C1 + C2) + (C3 + C4);
#pragma unroll
        for (int q = 0; q < 4; ++q)
            put_state(&H1H[0][4 * g + q][c], &H1L[0][4 * g + q][c],
                      fast_tanh(acc1[q]));
        BAR();
    }

    // Epilogue: out = sigmoid(h1(79) @ Wout + bout). Wave wid -> rows 4wid..+3.
#pragma unroll
    for (int q = 0; q < 4; ++q) {
        int row = 4 * wid + q;
        float v = u2f(((unsigned)H1H[0][row][l]) << 16) +
                  u2f(((unsigned)H1L[0][row][l]) << 16);
        float pp = v * woj;
#pragma unroll
        for (int off = 32; off > 0; off >>= 1) pp += __shfl_xor(pp, off, 64);
        if (l == 0) {
            float logit = pp + bout[0];
            out[R + row] = __builtin_amdgcn_rcpf(
                1.0f + __builtin_amdgcn_exp2f(-1.4426950408889634f * logit));
        }
    }
}

extern "C" void kernel_launch(void* const* d_in, const int* in_sizes, int n_in,
                              void* d_out, int out_size, void* d_ws, size_t ws_size,
                              hipStream_t stream) {
    const int*   tokens = (const int*)  d_in[0];
    const float* emb    = (const float*)d_in[1];
    const float* Wx0    = (const float*)d_in[2];
    const float* Wh0    = (const float*)d_in[3];
    const float* b0     = (const float*)d_in[4];
    const float* Wx1    = (const float*)d_in[5];
    const float* Wh1    = (const float*)d_in[6];
    const float* b1     = (const float*)d_in[7];
    const float* Wout   = (const float*)d_in[8];
    const float* bout   = (const float*)d_in[9];
    float* out  = (float*)d_out;
    float* emb2 = (float*)d_ws;   // VV*HH floats = 2.56 MB

    emb2_kernel<<<VV / 16, 256, 0, stream>>>(emb, Wx0, b0, emb2);
    rnn_pipe<<<BB / 16, 256, 0, stream>>>(tokens, emb2, Wh0, Wx1, Wh1, b1,
                                          Wout, bout, out);
}